// Round 8
// baseline (523.224 us; speedup 1.0000x reference)
//
#include <hip/hip_runtime.h>
#include <math.h>

// GAT, N=4096, ~1% adjacency. R8: fix GEMM LDS swizzle bit — chunk XOR key is
// (row>>1)&3 (not row&3): row stride is 64 B = half the 128-B bank cycle, so
// (ra&1) already picks low/high 16-B position group; XOR on (ra>>1)&3 spreads
// the 4 positions within each group -> 2-way aliasing (free) instead of 4-way.
// Rest identical to R7 (XCD-pinned gathers, dbuf 128x128 split-bf16 MFMA GEMM).

#define N_NODES 4096
#define MAXNB 128
#define BM 128
#define BN 128
#define BK 32

typedef short bf16x8 __attribute__((ext_vector_type(8)));
typedef float f32x4 __attribute__((ext_vector_type(4)));

#define GLL(gp, lp)                                                     \
  __builtin_amdgcn_global_load_lds(                                     \
      (const __attribute__((address_space(1))) void*)(gp),              \
      (__attribute__((address_space(3))) void*)(lp), 16, 0, 0)

// ---------------- bf16 helpers ----------------
__device__ __forceinline__ unsigned short bf16_rne(float f) {
  unsigned int u = __float_as_uint(f);
  unsigned int r = (u + 0x7FFFu + ((u >> 16) & 1u)) >> 16;
  return (unsigned short)r;
}
__device__ __forceinline__ float bf2f(unsigned short v) {
  return __uint_as_float((unsigned int)v << 16);
}
__device__ __forceinline__ void split_bf16(float f, unsigned short& h,
                                           unsigned short& l) {
  h = bf16_rne(f);
  l = bf16_rne(f - bf2f(h));
}

// ---------------- reduction helpers (blockDim == 256) ----------------
__device__ __forceinline__ float wave_sum(float v) {
#pragma unroll
  for (int o = 32; o > 0; o >>= 1) v += __shfl_xor(v, o);
  return v;
}
__device__ __forceinline__ float wave_max(float v) {
#pragma unroll
  for (int o = 32; o > 0; o >>= 1) v = fmaxf(v, __shfl_xor(v, o));
  return v;
}
__device__ __forceinline__ float block_sum(float v, float* buf) {
  v = wave_sum(v);
  __syncthreads();
  if ((threadIdx.x & 63) == 0) buf[threadIdx.x >> 6] = v;
  __syncthreads();
  return buf[0] + buf[1] + buf[2] + buf[3];
}
__device__ __forceinline__ float block_max(float v, float* buf) {
  v = wave_max(v);
  __syncthreads();
  if ((threadIdx.x & 63) == 0) buf[threadIdx.x >> 6] = v;
  __syncthreads();
  return fmaxf(fmaxf(buf[0], buf[1]), fmaxf(buf[2], buf[3]));
}

// ---------------- zero f-buffers ----------------
__global__ __launch_bounds__(256) void zero_f(float* __restrict__ p, int n) {
  int i = blockIdx.x * 256 + threadIdx.x;
  if (i < n) p[i] = 0.f;
}

// ---------------- CSR build ----------------
__global__ __launch_bounds__(256) void build_csr(const float* __restrict__ adj,
                                                 int* __restrict__ cnt,
                                                 int* __restrict__ idx) {
  __shared__ int c;
  if (threadIdx.x == 0) c = 0;
  __syncthreads();
  const int row = blockIdx.x;
  const float* arow = adj + (size_t)row * N_NODES;
  for (int b = 0; b < N_NODES; b += 256) {
    float v = arow[b + threadIdx.x];
    if (v > 0.f) {
      int p = atomicAdd(&c, 1);
      if (p < MAXNB) idx[row * MAXNB + p] = b + threadIdx.x;
    }
  }
  __syncthreads();
  if (threadIdx.x == 0) cnt[row] = c < MAXNB ? c : MAXNB;
}

// ---------------- elementwise fp32 -> bf16 hi/lo ----------------
__global__ __launch_bounds__(256) void convert_split(const float* __restrict__ in,
                                                     unsigned short* __restrict__ oh,
                                                     unsigned short* __restrict__ ol,
                                                     int n4) {
  int i = blockIdx.x * 256 + threadIdx.x;
  if (i >= n4) return;
  float4 v = ((const float4*)in)[i];
  ushort4 h, l;
  split_bf16(v.x, h.x, l.x);
  split_bf16(v.y, h.y, l.y);
  split_bf16(v.z, h.z, l.z);
  split_bf16(v.w, h.w, l.w);
  ((ushort4*)oh)[i] = h;
  ((ushort4*)ol)[i] = l;
}

// ---------------- W [H][K][D] fp32 -> Bt [H*D][K] bf16 hi/lo ----------------
__global__ __launch_bounds__(256) void convert_w(const float* __restrict__ W,
                                                 unsigned short* __restrict__ th,
                                                 unsigned short* __restrict__ tl,
                                                 int K, int D) {
  __shared__ float t[32][33];
  const int h = blockIdx.z;
  const int k0 = blockIdx.x * 32, d0 = blockIdx.y * 32;
  const int tx = threadIdx.x & 31, ty = threadIdx.x >> 5;
  const float* Wp = W + (size_t)h * K * D;
#pragma unroll
  for (int r = 0; r < 4; r++)
    t[ty + r * 8][tx] = Wp[(size_t)(k0 + ty + r * 8) * D + d0 + tx];
  __syncthreads();
#pragma unroll
  for (int r = 0; r < 4; r++) {
    int d = ty + r * 8;
    float v = t[tx][d];
    unsigned short hh, ll;
    split_bf16(v, hh, ll);
    size_t o = (size_t)(h * D + d0 + d) * K + k0 + tx;
    th[o] = hh;
    tl[o] = ll;
  }
}

// ---------------- split-bf16 MFMA GEMM: 128x128 tile, dbuf, 2-way-free swizzle ----------------
__global__ __launch_bounds__(256) void gemm_mfma(
    const unsigned short* __restrict__ Ah, const unsigned short* __restrict__ Al,
    const unsigned short* __restrict__ Bh, const unsigned short* __restrict__ Bl,
    unsigned short* __restrict__ Cb, float* __restrict__ f1,
    float* __restrict__ f2, const float* __restrict__ af, int K, int Ntot, int D) {
  __shared__ unsigned short lds[2][4][BM * BK];  // 64 KB: [buf][Ah,Al,Bh,Bl]

  const int tid = threadIdx.x;
  const int w = tid >> 6, lane = tid & 63;
  const int wm = w >> 1, wn = w & 1;
  const int quad = lane >> 4, l16 = lane & 15;
  const int m0 = blockIdx.x * BM, n0 = blockIdx.y * BN;

  // slot s (16B chunks): row = s>>2, holds global chunk (s&3) ^ ((row>>1)&3)
  const int s0 = w * 128 + lane, s1 = s0 + 64;
  const int r0 = s0 >> 2, q0 = (s0 & 3) ^ ((r0 >> 1) & 3);
  const int r1 = s1 >> 2, q1 = (s1 & 3) ^ ((r1 >> 1) & 3);
  const size_t offA0 = (size_t)(m0 + r0) * K + q0 * 8;
  const size_t offA1 = (size_t)(m0 + r1) * K + q1 * 8;
  const size_t offB0 = (size_t)(n0 + r0) * K + q0 * 8;
  const size_t offB1 = (size_t)(n0 + r1) * K + q1 * 8;

#define STAGE(b, k0)                                  \
  do {                                                \
    GLL(Ah + offA0 + (k0), &lds[b][0][s0 * 8]);       \
    GLL(Ah + offA1 + (k0), &lds[b][0][s1 * 8]);       \
    GLL(Al + offA0 + (k0), &lds[b][1][s0 * 8]);       \
    GLL(Al + offA1 + (k0), &lds[b][1][s1 * 8]);       \
    GLL(Bh + offB0 + (k0), &lds[b][2][s0 * 8]);       \
    GLL(Bh + offB1 + (k0), &lds[b][2][s1 * 8]);       \
    GLL(Bl + offB0 + (k0), &lds[b][3][s0 * 8]);       \
    GLL(Bl + offB1 + (k0), &lds[b][3][s1 * 8]);       \
  } while (0)

  f32x4 acc[4][4];
#pragma unroll
  for (int i = 0; i < 4; i++)
#pragma unroll
    for (int j = 0; j < 4; j++) acc[i][j] = (f32x4){0.f, 0.f, 0.f, 0.f};

  // fragment read: row ra wants global chunk `quad` -> stored at pos quad^((ra>>1)&3)
  int posA[4], posB[4];
#pragma unroll
  for (int i = 0; i < 4; i++) {
    int ra = wm * 64 + i * 16 + l16;
    posA[i] = (ra * 4 + (quad ^ ((ra >> 1) & 3))) * 8;
    int rb = wn * 64 + i * 16 + l16;
    posB[i] = (rb * 4 + (quad ^ ((rb >> 1) & 3))) * 8;
  }

  const int KT = K / BK;
  STAGE(0, 0);
  for (int kt = 0; kt < KT; kt++) {
    const int cur = kt & 1;
    __syncthreads();
    if (kt + 1 < KT) STAGE(cur ^ 1, (kt + 1) * BK);

    bf16x8 fah[4], fal[4], fbh[4], fbl[4];
#pragma unroll
    for (int i = 0; i < 4; i++) {
      fah[i] = *(const bf16x8*)&lds[cur][0][posA[i]];
      fal[i] = *(const bf16x8*)&lds[cur][1][posA[i]];
      fbh[i] = *(const bf16x8*)&lds[cur][2][posB[i]];
      fbl[i] = *(const bf16x8*)&lds[cur][3][posB[i]];
    }
#pragma unroll
    for (int i = 0; i < 4; i++)
#pragma unroll
      for (int j = 0; j < 4; j++) {
        acc[i][j] = __builtin_amdgcn_mfma_f32_16x16x32_bf16(fah[i], fbh[j],
                                                            acc[i][j], 0, 0, 0);
        acc[i][j] = __builtin_amdgcn_mfma_f32_16x16x32_bf16(fah[i], fbl[j],
                                                            acc[i][j], 0, 0, 0);
        acc[i][j] = __builtin_amdgcn_mfma_f32_16x16x32_bf16(fal[i], fbh[j],
                                                            acc[i][j], 0, 0, 0);
      }
  }
#undef STAGE

  const int gm = m0 + wm * 64 + quad * 4;
  const int gn = n0 + wn * 64 + l16;
#pragma unroll
  for (int i = 0; i < 4; i++)
#pragma unroll
    for (int j = 0; j < 4; j++) {
      unsigned short* p = Cb + (size_t)(gm + i * 16) * Ntot + gn + j * 16;
#pragma unroll
      for (int r = 0; r < 4; r++) p[(size_t)r * Ntot] = bf16_rne(acc[i][j][r]);
    }

  const int h = n0 / D;
  const int d0 = (n0 % D) + wn * 64 + l16;
  float a1v[4], a2v[4];
#pragma unroll
  for (int j = 0; j < 4; j++) {
    a1v[j] = af[h * 2 * D + d0 + j * 16];
    a2v[j] = af[h * 2 * D + D + d0 + j * 16];
  }
#pragma unroll
  for (int i = 0; i < 4; i++)
#pragma unroll
    for (int r = 0; r < 4; r++) {
      float s1 = 0.f, s2 = 0.f;
#pragma unroll
      for (int j = 0; j < 4; j++) {
        s1 += acc[i][j][r] * a1v[j];
        s2 += acc[i][j][r] * a2v[j];
      }
#pragma unroll
      for (int m = 1; m < 16; m <<= 1) {
        s1 += __shfl_xor(s1, m);
        s2 += __shfl_xor(s2, m);
      }
      if (l16 == 0) {
        int row = gm + i * 16 + r;
        atomicAdd(&f1[h * N_NODES + row], s1);
        atomicAdd(&f2[h * N_NODES + row], s2);
      }
    }
}

// ---------------- attention weights: softmax over neighbors, per head ----------------
__global__ __launch_bounds__(256) void attw(const float* __restrict__ f1,
                                            const float* __restrict__ f2,
                                            const int* __restrict__ cnt,
                                            const int* __restrict__ idxs,
                                            float* __restrict__ wgt, int H,
                                            float scale) {
  __shared__ int nbs[MAXNB];
  __shared__ float buf[4];
  const int n = blockIdx.x, tid = threadIdx.x;
  const int c = cnt[n];
  if (tid < c) nbs[tid] = idxs[n * MAXNB + tid];
  __syncthreads();
  for (int h = 0; h < H; h++) {
    float e = -3.0e38f;
    if (tid < c) {
      float s = f1[h * N_NODES + n] + f2[h * N_NODES + nbs[tid]];
      e = s >= 0.f ? s : 0.2f * s;  // leaky_relu
    }
    float m = block_max(e, buf);
    float wj = (tid < c) ? __expf(e - m) : 0.f;
    float tot = block_sum(wj, buf);
    if (tid < c) wgt[((size_t)h * N_NODES + n) * MAXNB + tid] = wj / tot * scale;
  }
}

// ---------------- layers 1&2 gather: 8 XCD-pinned 128-col tiles ----------------
__global__ __launch_bounds__(256) void gather12(
    const unsigned short* __restrict__ Whb, const float* __restrict__ wgt,
    const int* __restrict__ cnt, const int* __restrict__ idxs,
    unsigned short* __restrict__ hh, unsigned short* __restrict__ hl) {
  __shared__ int snb[4][MAXNB];
  __shared__ float swt[4][MAXNB];
  const int t = blockIdx.x & 7;
  const int g = blockIdx.x >> 3;
  const int tid = threadIdx.x;
  const int h = t >> 1;  // 2 tiles per head (D=256)
  for (int i = tid; i < 4 * MAXNB; i += 256) {
    int ni = i >> 7, j = i & (MAXNB - 1);
    snb[ni][j] = idxs[(g * 4 + ni) * MAXNB + j];
    swt[ni][j] = wgt[((size_t)h * N_NODES + g * 4 + ni) * MAXNB + j];
  }
  __syncthreads();
  const int w = tid >> 6, lane = tid & 63;
  const int n = g * 4 + w;
  const int c = cnt[n];
  const int col = t * 128 + lane * 2;
  float a0 = 0.f, a1 = 0.f;
  for (int j = 0; j < c; j++) {
    const int nb = snb[w][j];
    const float wv = swt[w][j];
    ushort2 v = *(const ushort2*)(Whb + (size_t)nb * 1024 + col);
    a0 += wv * bf2f(v.x);
    a1 += wv * bf2f(v.y);
  }
  float o[2] = {a0, a1};
  ushort2 oh, ol;
#pragma unroll
  for (int s = 0; s < 2; s++) {
    float v = o[s];
    v = v > 0.f ? v : __expf(v) - 1.f;  // elu (per-head)
    v = v > 0.f ? v : __expf(v) - 1.f;  // elu (post-concat)
    unsigned short vh, vl;
    split_bf16(v, vh, vl);
    ((unsigned short*)&oh)[s] = vh;
    ((unsigned short*)&ol)[s] = vl;
  }
  *(ushort2*)(hh + (size_t)n * 1024 + col) = oh;
  *(ushort2*)(hl + (size_t)n * 1024 + col) = ol;
}

// ---------------- layer 3 gather: 24 XCD-pinned 128-col tiles ----------------
__global__ __launch_bounds__(256) void gather3(
    const unsigned short* __restrict__ Whb, const float* __restrict__ wgt,
    const int* __restrict__ cnt, const int* __restrict__ idxs,
    unsigned short* __restrict__ aggb) {
  __shared__ int snb[4][MAXNB];
  __shared__ float swt[4][MAXNB];
  const int t = blockIdx.x % 24;
  const int g = blockIdx.x / 24;
  const int tid = threadIdx.x;
  const int h = t >> 2;  // 4 tiles per head (D=512)
  for (int i = tid; i < 4 * MAXNB; i += 256) {
    int ni = i >> 7, j = i & (MAXNB - 1);
    snb[ni][j] = idxs[(g * 4 + ni) * MAXNB + j];
    swt[ni][j] = wgt[((size_t)h * N_NODES + g * 4 + ni) * MAXNB + j];
  }
  __syncthreads();
  const int w = tid >> 6, lane = tid & 63;
  const int n = g * 4 + w;
  const int c = cnt[n];
  const int col = t * 128 + lane * 2;   // global col in 3072
  const int cc = col - h * 512;         // col within head
  float a0 = 0.f, a1 = 0.f;
  for (int j = 0; j < c; j++) {
    const int nb = snb[w][j];
    const float wv = swt[w][j];
    ushort2 v = *(const ushort2*)(Whb + (size_t)nb * 3072 + col);
    a0 += wv * bf2f(v.x);
    a1 += wv * bf2f(v.y);
  }
  ushort2 o;
  o.x = bf16_rne(a0);
  o.y = bf16_rne(a1);
  *(ushort2*)(aggb + ((size_t)h * N_NODES + n) * 512 + cc) = o;
}

// ---------------- layer 3 reduce: head-sum + elu + L2-normalize ----------------
__global__ __launch_bounds__(256) void reduce3(const unsigned short* __restrict__ aggb,
                                               float* __restrict__ out) {
  __shared__ float buf[4];
  const int n = blockIdx.x, tid = threadIdx.x;
  float v0 = 0.f, v1 = 0.f;
#pragma unroll
  for (int h = 0; h < 6; h++) {
    ushort2 u = *(const ushort2*)(aggb + ((size_t)h * N_NODES + n) * 512 + tid * 2);
    v0 += bf2f(u.x);
    v1 += bf2f(u.y);
  }
  v0 = v0 > 0.f ? v0 : __expf(v0) - 1.f;
  v1 = v1 > 0.f ? v1 : __expf(v1) - 1.f;
  float ss = block_sum(v0 * v0 + v1 * v1, buf);
  float inv = 1.f / fmaxf(sqrtf(ss), 1e-12f);
  out[(size_t)n * 512 + tid * 2] = v0 * inv;
  out[(size_t)n * 512 + tid * 2 + 1] = v1 * inv;
}

extern "C" void kernel_launch(void* const* d_in, const int* in_sizes, int n_in,
                              void* d_out, int out_size, void* d_ws, size_t ws_size,
                              hipStream_t stream) {
  (void)in_sizes; (void)n_in; (void)out_size; (void)ws_size;
  const float* x   = (const float*)d_in[0];  // [4096, 2048]
  const float* adj = (const float*)d_in[1];  // [4096, 4096]
  const float* W1  = (const float*)d_in[2];  // [4, 2048, 256]
  const float* a1  = (const float*)d_in[3];  // [4, 512]
  const float* W2  = (const float*)d_in[4];  // [4, 1024, 256]
  const float* a2  = (const float*)d_in[5];  // [4, 512]
  const float* W3  = (const float*)d_in[6];  // [6, 1024, 512]
  const float* a3  = (const float*)d_in[7];  // [6, 1024]
  float* out = (float*)d_out;                // [4096, 512]

  // workspace layout (~74 MB peak; overlays on dead regions)
  char* ws = (char*)d_ws;
  size_t off = 0;
  auto alloc = [&](size_t bytes) {
    void* p = ws + off;
    off += (bytes + 255) & ~(size_t)255;
    return p;
  };
  int* nbr_cnt = (int*)alloc((size_t)N_NODES * 4);
  int* nbr_idx = (int*)alloc((size_t)N_NODES * MAXNB * 4);
  float* fbuf = (float*)alloc((size_t)28 * N_NODES * 4);
  unsigned short* Wt_h = (unsigned short*)alloc((size_t)6 * 1024 * 512 * 2);
  unsigned short* Wt_l = (unsigned short*)alloc((size_t)6 * 1024 * 512 * 2);
  unsigned short* R = (unsigned short*)alloc((size_t)N_NODES * 2048 * 2 * 2);
  unsigned short* Whb = (unsigned short*)alloc((size_t)N_NODES * 3072 * 2);

  unsigned short* xh = R;                               // layer-1 A (dead after gemm1)
  unsigned short* xl = R + (size_t)N_NODES * 2048;
  unsigned short* hh = R;                               // layer outputs
  unsigned short* hl = R + (size_t)N_NODES * 1024;
  float* wgt12 = (float*)((char*)R + (size_t)N_NODES * 2048 * 2);  // dead xl half
  float* wgt3 = (float*)Wt_h;                           // dead after gemm3
  unsigned short* aggb = R;                             // dead after gemm3

  float* f1_1 = fbuf;
  float* f2_1 = fbuf + 4 * N_NODES;
  float* f1_2 = fbuf + 8 * N_NODES;
  float* f2_2 = fbuf + 12 * N_NODES;
  float* f1_3 = fbuf + 16 * N_NODES;
  float* f2_3 = fbuf + 22 * N_NODES;

  zero_f<<<(28 * N_NODES + 255) / 256, 256, 0, stream>>>(fbuf, 28 * N_NODES);
  build_csr<<<N_NODES, 256, 0, stream>>>(adj, nbr_cnt, nbr_idx);

  // ---- layer 1: A = x (K=2048), Ntot = 1024, D = 256 ----
  convert_split<<<(N_NODES * 2048 / 4 + 255) / 256, 256, 0, stream>>>(
      x, xh, xl, N_NODES * 2048 / 4);
  convert_w<<<dim3(2048 / 32, 256 / 32, 4), 256, 0, stream>>>(W1, Wt_h, Wt_l, 2048, 256);
  gemm_mfma<<<dim3(N_NODES / BM, 1024 / BN), 256, 0, stream>>>(
      xh, xl, Wt_h, Wt_l, Whb, f1_1, f2_1, a1, 2048, 1024, 256);
  attw<<<N_NODES, 256, 0, stream>>>(f1_1, f2_1, nbr_cnt, nbr_idx, wgt12, 4, 1.f);
  gather12<<<8 * (N_NODES / 4), 256, 0, stream>>>(Whb, wgt12, nbr_cnt, nbr_idx,
                                                  hh, hl);

  // ---- layer 2: A = h (K=1024), Ntot = 1024, D = 256 ----
  convert_w<<<dim3(1024 / 32, 256 / 32, 4), 256, 0, stream>>>(W2, Wt_h, Wt_l, 1024, 256);
  gemm_mfma<<<dim3(N_NODES / BM, 1024 / BN), 256, 0, stream>>>(
      hh, hl, Wt_h, Wt_l, Whb, f1_2, f2_2, a2, 1024, 1024, 256);
  attw<<<N_NODES, 256, 0, stream>>>(f1_2, f2_2, nbr_cnt, nbr_idx, wgt12, 4, 1.f);
  gather12<<<8 * (N_NODES / 4), 256, 0, stream>>>(Whb, wgt12, nbr_cnt, nbr_idx,
                                                  hh, hl);

  // ---- layer 3: A = h (K=1024), Ntot = 3072, D = 512 ----
  convert_w<<<dim3(1024 / 32, 512 / 32, 6), 256, 0, stream>>>(W3, Wt_h, Wt_l, 1024, 512);
  gemm_mfma<<<dim3(N_NODES / BM, 3072 / BN), 256, 0, stream>>>(
      hh, hl, Wt_h, Wt_l, Whb, f1_3, f2_3, a3, 1024, 3072, 512);
  attw<<<N_NODES, 256, 0, stream>>>(f1_3, f2_3, nbr_cnt, nbr_idx, wgt3, 6, 1.f / 6.f);
  gather3<<<24 * (N_NODES / 4), 256, 0, stream>>>(Whb, wgt3, nbr_cnt, nbr_idx, aggb);
  reduce3<<<N_NODES, 256, 0, stream>>>(aggb, out);
}

// Round 9
// 441.922 us; speedup vs baseline: 1.1840x; 1.1840x over previous
//
#include <hip/hip_runtime.h>
#include <math.h>

// GAT, N=4096, ~1% adjacency. R9: fp16 end-to-end.
// fp16 (11-bit mantissa) input/weight/Wh/h storage: value-path error ~2.4e-4 rel
// (8x better than bf16 storage) and a SINGLE mfma_f32_16x16x32_f16 pass replaces
// the 3-pass split-bf16 GEMM -> 3x less MFMA, 2x less LDS/staging, 32KB LDS
// (4-5 blocks/CU). f1/f2 logits still exact-from-fp32-acc in the GEMM epilogue.
// Gathers: R7/R8 XCD-pinned column tiles. Swizzle: R8 conflict-free form.

#define N_NODES 4096
#define MAXNB 128
#define BM 128
#define BN 128
#define BK 32

typedef _Float16 f16x8 __attribute__((ext_vector_type(8)));
typedef float f32x4 __attribute__((ext_vector_type(4)));

#define GLL(gp, lp)                                                     \
  __builtin_amdgcn_global_load_lds(                                     \
      (const __attribute__((address_space(1))) void*)(gp),              \
      (__attribute__((address_space(3))) void*)(lp), 16, 0, 0)

// ---------------- fp16 helpers ----------------
union U16 {
  unsigned short u;
  _Float16 h;
};
__device__ __forceinline__ float h2f(unsigned short u) {
  U16 x;
  x.u = u;
  return (float)x.h;
}
__device__ __forceinline__ unsigned short f2h(float f) {
  U16 x;
  x.h = (_Float16)f;  // RNE
  return x.u;
}

// ---------------- reduction helpers (blockDim == 256) ----------------
__device__ __forceinline__ float wave_sum(float v) {
#pragma unroll
  for (int o = 32; o > 0; o >>= 1) v += __shfl_xor(v, o);
  return v;
}
__device__ __forceinline__ float wave_max(float v) {
#pragma unroll
  for (int o = 32; o > 0; o >>= 1) v = fmaxf(v, __shfl_xor(v, o));
  return v;
}
__device__ __forceinline__ float block_sum(float v, float* buf) {
  v = wave_sum(v);
  __syncthreads();
  if ((threadIdx.x & 63) == 0) buf[threadIdx.x >> 6] = v;
  __syncthreads();
  return buf[0] + buf[1] + buf[2] + buf[3];
}
__device__ __forceinline__ float block_max(float v, float* buf) {
  v = wave_max(v);
  __syncthreads();
  if ((threadIdx.x & 63) == 0) buf[threadIdx.x >> 6] = v;
  __syncthreads();
  return fmaxf(fmaxf(buf[0], buf[1]), fmaxf(buf[2], buf[3]));
}

// ---------------- zero f-buffers ----------------
__global__ __launch_bounds__(256) void zero_f(float* __restrict__ p, int n) {
  int i = blockIdx.x * 256 + threadIdx.x;
  if (i < n) p[i] = 0.f;
}

// ---------------- CSR build ----------------
__global__ __launch_bounds__(256) void build_csr(const float* __restrict__ adj,
                                                 int* __restrict__ cnt,
                                                 int* __restrict__ idx) {
  __shared__ int c;
  if (threadIdx.x == 0) c = 0;
  __syncthreads();
  const int row = blockIdx.x;
  const float* arow = adj + (size_t)row * N_NODES;
  for (int b = 0; b < N_NODES; b += 256) {
    float v = arow[b + threadIdx.x];
    if (v > 0.f) {
      int p = atomicAdd(&c, 1);
      if (p < MAXNB) idx[row * MAXNB + p] = b + threadIdx.x;
    }
  }
  __syncthreads();
  if (threadIdx.x == 0) cnt[row] = c < MAXNB ? c : MAXNB;
}

// ---------------- elementwise fp32 -> fp16 ----------------
__global__ __launch_bounds__(256) void convert_h(const float* __restrict__ in,
                                                 unsigned short* __restrict__ oh,
                                                 int n4) {
  int i = blockIdx.x * 256 + threadIdx.x;
  if (i >= n4) return;
  float4 v = ((const float4*)in)[i];
  ushort4 h;
  h.x = f2h(v.x);
  h.y = f2h(v.y);
  h.z = f2h(v.z);
  h.w = f2h(v.w);
  ((ushort4*)oh)[i] = h;
}

// ---------------- W [H][K][D] fp32 -> Bt [H*D][K] fp16 ----------------
__global__ __launch_bounds__(256) void convert_w(const float* __restrict__ W,
                                                 unsigned short* __restrict__ th,
                                                 int K, int D) {
  __shared__ float t[32][33];
  const int h = blockIdx.z;
  const int k0 = blockIdx.x * 32, d0 = blockIdx.y * 32;
  const int tx = threadIdx.x & 31, ty = threadIdx.x >> 5;
  const float* Wp = W + (size_t)h * K * D;
#pragma unroll
  for (int r = 0; r < 4; r++)
    t[ty + r * 8][tx] = Wp[(size_t)(k0 + ty + r * 8) * D + d0 + tx];
  __syncthreads();
#pragma unroll
  for (int r = 0; r < 4; r++) {
    int d = ty + r * 8;
    th[(size_t)(h * D + d0 + d) * K + k0 + tx] = f2h(t[tx][d]);
  }
}

// ---------------- fp16 MFMA GEMM: 128x128 tile, dbuf, conflict-free swizzle ----------------
// Cb[M][Ntot] (fp16) = A[M][K] @ Bt[Ntot][K]^T (A/B fp16).
// 256 threads = 4 waves (2x2), each wave 64x64 via 4x4 16x16x32 frags, 1 pass.
// LDS slot s (16B chunks): row=s>>2, holds chunk (s&3)^((row>>1)&3).
// f1/f2 exact from fp32 acc (shfl + atomicAdd).
__global__ __launch_bounds__(256) void gemm_mfma(
    const unsigned short* __restrict__ A, const unsigned short* __restrict__ B,
    unsigned short* __restrict__ Cb, float* __restrict__ f1,
    float* __restrict__ f2, const float* __restrict__ af, int K, int Ntot, int D) {
  __shared__ unsigned short lds[2][2][BM * BK];  // 32 KB: [buf][A,B]

  const int tid = threadIdx.x;
  const int w = tid >> 6, lane = tid & 63;
  const int wm = w >> 1, wn = w & 1;
  const int quad = lane >> 4, l16 = lane & 15;
  const int m0 = blockIdx.x * BM, n0 = blockIdx.y * BN;

  const int s0 = w * 128 + lane, s1 = s0 + 64;
  const int r0 = s0 >> 2, q0 = (s0 & 3) ^ ((r0 >> 1) & 3);
  const int r1 = s1 >> 2, q1 = (s1 & 3) ^ ((r1 >> 1) & 3);
  const size_t offA0 = (size_t)(m0 + r0) * K + q0 * 8;
  const size_t offA1 = (size_t)(m0 + r1) * K + q1 * 8;
  const size_t offB0 = (size_t)(n0 + r0) * K + q0 * 8;
  const size_t offB1 = (size_t)(n0 + r1) * K + q1 * 8;

#define STAGE(b, k0)                                \
  do {                                              \
    GLL(A + offA0 + (k0), &lds[b][0][s0 * 8]);      \
    GLL(A + offA1 + (k0), &lds[b][0][s1 * 8]);      \
    GLL(B + offB0 + (k0), &lds[b][1][s0 * 8]);      \
    GLL(B + offB1 + (k0), &lds[b][1][s1 * 8]);      \
  } while (0)

  f32x4 acc[4][4];
#pragma unroll
  for (int i = 0; i < 4; i++)
#pragma unroll
    for (int j = 0; j < 4; j++) acc[i][j] = (f32x4){0.f, 0.f, 0.f, 0.f};

  // fragment read: row ra wants chunk `quad` -> stored at quad^((ra>>1)&3)
  int posA[4], posB[4];
#pragma unroll
  for (int i = 0; i < 4; i++) {
    int ra = wm * 64 + i * 16 + l16;
    posA[i] = (ra * 4 + (quad ^ ((ra >> 1) & 3))) * 8;
    int rb = wn * 64 + i * 16 + l16;
    posB[i] = (rb * 4 + (quad ^ ((rb >> 1) & 3))) * 8;
  }

  const int KT = K / BK;
  STAGE(0, 0);
  for (int kt = 0; kt < KT; kt++) {
    const int cur = kt & 1;
    __syncthreads();
    if (kt + 1 < KT) STAGE(cur ^ 1, (kt + 1) * BK);

    f16x8 fa[4], fb[4];
#pragma unroll
    for (int i = 0; i < 4; i++) {
      fa[i] = *(const f16x8*)&lds[cur][0][posA[i]];
      fb[i] = *(const f16x8*)&lds[cur][1][posB[i]];
    }
#pragma unroll
    for (int i = 0; i < 4; i++)
#pragma unroll
      for (int j = 0; j < 4; j++)
        acc[i][j] = __builtin_amdgcn_mfma_f32_16x16x32_f16(fa[i], fb[j],
                                                           acc[i][j], 0, 0, 0);
  }
#undef STAGE

  // epilogue 1: fp16 C write (C/D layout: col=l16, row=quad*4+r)
  const int gm = m0 + wm * 64 + quad * 4;
  const int gn = n0 + wn * 64 + l16;
#pragma unroll
  for (int i = 0; i < 4; i++)
#pragma unroll
    for (int j = 0; j < 4; j++) {
      unsigned short* p = Cb + (size_t)(gm + i * 16) * Ntot + gn + j * 16;
#pragma unroll
      for (int r = 0; r < 4; r++) p[(size_t)r * Ntot] = f2h(acc[i][j][r]);
    }

  // epilogue 2: exact f1/f2 from fp32 acc (block spans one head: 128 | D)
  const int h = n0 / D;
  const int d0 = (n0 % D) + wn * 64 + l16;
  float a1v[4], a2v[4];
#pragma unroll
  for (int j = 0; j < 4; j++) {
    a1v[j] = af[h * 2 * D + d0 + j * 16];
    a2v[j] = af[h * 2 * D + D + d0 + j * 16];
  }
#pragma unroll
  for (int i = 0; i < 4; i++)
#pragma unroll
    for (int r = 0; r < 4; r++) {
      float s1 = 0.f, s2 = 0.f;
#pragma unroll
      for (int j = 0; j < 4; j++) {
        s1 += acc[i][j][r] * a1v[j];
        s2 += acc[i][j][r] * a2v[j];
      }
#pragma unroll
      for (int m = 1; m < 16; m <<= 1) {
        s1 += __shfl_xor(s1, m);
        s2 += __shfl_xor(s2, m);
      }
      if (l16 == 0) {
        int row = gm + i * 16 + r;
        atomicAdd(&f1[h * N_NODES + row], s1);
        atomicAdd(&f2[h * N_NODES + row], s2);
      }
    }
}

// ---------------- attention weights: softmax over neighbors, per head ----------------
__global__ __launch_bounds__(256) void attw(const float* __restrict__ f1,
                                            const float* __restrict__ f2,
                                            const int* __restrict__ cnt,
                                            const int* __restrict__ idxs,
                                            float* __restrict__ wgt, int H,
                                            float scale) {
  __shared__ int nbs[MAXNB];
  __shared__ float buf[4];
  const int n = blockIdx.x, tid = threadIdx.x;
  const int c = cnt[n];
  if (tid < c) nbs[tid] = idxs[n * MAXNB + tid];
  __syncthreads();
  for (int h = 0; h < H; h++) {
    float e = -3.0e38f;
    if (tid < c) {
      float s = f1[h * N_NODES + n] + f2[h * N_NODES + nbs[tid]];
      e = s >= 0.f ? s : 0.2f * s;  // leaky_relu
    }
    float m = block_max(e, buf);
    float wj = (tid < c) ? __expf(e - m) : 0.f;
    float tot = block_sum(wj, buf);
    if (tid < c) wgt[((size_t)h * N_NODES + n) * MAXNB + tid] = wj / tot * scale;
  }
}

// ---------------- layers 1&2 gather: 8 XCD-pinned 128-col tiles ----------------
__global__ __launch_bounds__(256) void gather12(
    const unsigned short* __restrict__ Whb, const float* __restrict__ wgt,
    const int* __restrict__ cnt, const int* __restrict__ idxs,
    unsigned short* __restrict__ hh) {
  __shared__ int snb[4][MAXNB];
  __shared__ float swt[4][MAXNB];
  const int t = blockIdx.x & 7;
  const int g = blockIdx.x >> 3;
  const int tid = threadIdx.x;
  const int h = t >> 1;  // 2 tiles per head (D=256)
  for (int i = tid; i < 4 * MAXNB; i += 256) {
    int ni = i >> 7, j = i & (MAXNB - 1);
    snb[ni][j] = idxs[(g * 4 + ni) * MAXNB + j];
    swt[ni][j] = wgt[((size_t)h * N_NODES + g * 4 + ni) * MAXNB + j];
  }
  __syncthreads();
  const int w = tid >> 6, lane = tid & 63;
  const int n = g * 4 + w;
  const int c = cnt[n];
  const int col = t * 128 + lane * 2;
  float a0 = 0.f, a1 = 0.f;
  for (int j = 0; j < c; j++) {
    const int nb = snb[w][j];
    const float wv = swt[w][j];
    ushort2 v = *(const ushort2*)(Whb + (size_t)nb * 1024 + col);
    a0 += wv * h2f(v.x);
    a1 += wv * h2f(v.y);
  }
  float o[2] = {a0, a1};
  ushort2 oh;
#pragma unroll
  for (int s = 0; s < 2; s++) {
    float v = o[s];
    v = v > 0.f ? v : __expf(v) - 1.f;  // elu (per-head)
    v = v > 0.f ? v : __expf(v) - 1.f;  // elu (post-concat)
    ((unsigned short*)&oh)[s] = f2h(v);
  }
  *(ushort2*)(hh + (size_t)n * 1024 + col) = oh;
}

// ---------------- layer 3 gather: 24 XCD-pinned 128-col tiles ----------------
__global__ __launch_bounds__(256) void gather3(
    const unsigned short* __restrict__ Whb, const float* __restrict__ wgt,
    const int* __restrict__ cnt, const int* __restrict__ idxs,
    unsigned short* __restrict__ aggb) {
  __shared__ int snb[4][MAXNB];
  __shared__ float swt[4][MAXNB];
  const int t = blockIdx.x % 24;
  const int g = blockIdx.x / 24;
  const int tid = threadIdx.x;
  const int h = t >> 2;  // 4 tiles per head (D=512)
  for (int i = tid; i < 4 * MAXNB; i += 256) {
    int ni = i >> 7, j = i & (MAXNB - 1);
    snb[ni][j] = idxs[(g * 4 + ni) * MAXNB + j];
    swt[ni][j] = wgt[((size_t)h * N_NODES + g * 4 + ni) * MAXNB + j];
  }
  __syncthreads();
  const int w = tid >> 6, lane = tid & 63;
  const int n = g * 4 + w;
  const int c = cnt[n];
  const int col = t * 128 + lane * 2;   // global col in 3072
  const int cc = col - h * 512;         // col within head
  float a0 = 0.f, a1 = 0.f;
  for (int j = 0; j < c; j++) {
    const int nb = snb[w][j];
    const float wv = swt[w][j];
    ushort2 v = *(const ushort2*)(Whb + (size_t)nb * 3072 + col);
    a0 += wv * h2f(v.x);
    a1 += wv * h2f(v.y);
  }
  ushort2 o;
  o.x = f2h(a0);
  o.y = f2h(a1);
  *(ushort2*)(aggb + ((size_t)h * N_NODES + n) * 512 + cc) = o;
}

// ---------------- layer 3 reduce: head-sum + elu + L2-normalize ----------------
__global__ __launch_bounds__(256) void reduce3(const unsigned short* __restrict__ aggb,
                                               float* __restrict__ out) {
  __shared__ float buf[4];
  const int n = blockIdx.x, tid = threadIdx.x;
  float v0 = 0.f, v1 = 0.f;
#pragma unroll
  for (int h = 0; h < 6; h++) {
    ushort2 u = *(const ushort2*)(aggb + ((size_t)h * N_NODES + n) * 512 + tid * 2);
    v0 += h2f(u.x);
    v1 += h2f(u.y);
  }
  v0 = v0 > 0.f ? v0 : __expf(v0) - 1.f;
  v1 = v1 > 0.f ? v1 : __expf(v1) - 1.f;
  float ss = block_sum(v0 * v0 + v1 * v1, buf);
  float inv = 1.f / fmaxf(sqrtf(ss), 1e-12f);
  out[(size_t)n * 512 + tid * 2] = v0 * inv;
  out[(size_t)n * 512 + tid * 2 + 1] = v1 * inv;
}

extern "C" void kernel_launch(void* const* d_in, const int* in_sizes, int n_in,
                              void* d_out, int out_size, void* d_ws, size_t ws_size,
                              hipStream_t stream) {
  (void)in_sizes; (void)n_in; (void)out_size; (void)ws_size;
  const float* x   = (const float*)d_in[0];  // [4096, 2048]
  const float* adj = (const float*)d_in[1];  // [4096, 4096]
  const float* W1  = (const float*)d_in[2];  // [4, 2048, 256]
  const float* a1  = (const float*)d_in[3];  // [4, 512]
  const float* W2  = (const float*)d_in[4];  // [4, 1024, 256]
  const float* a2  = (const float*)d_in[5];  // [4, 512]
  const float* W3  = (const float*)d_in[6];  // [6, 1024, 512]
  const float* a3  = (const float*)d_in[7];  // [6, 1024]
  float* out = (float*)d_out;                // [4096, 512]

  // workspace layout (~76 MB peak)
  char* ws = (char*)d_ws;
  size_t off = 0;
  auto alloc = [&](size_t bytes) {
    void* p = ws + off;
    off += (bytes + 255) & ~(size_t)255;
    return p;
  };
  int* nbr_cnt = (int*)alloc((size_t)N_NODES * 4);
  int* nbr_idx = (int*)alloc((size_t)N_NODES * MAXNB * 4);
  float* fbuf = (float*)alloc((size_t)28 * N_NODES * 4);
  unsigned short* Wt = (unsigned short*)alloc((size_t)6 * 1024 * 512 * 2);  // 6.3 MB
  unsigned short* Areg = (unsigned short*)alloc((size_t)N_NODES * 2048 * 2);  // 16.8 MB
  unsigned short* Whb = (unsigned short*)alloc((size_t)N_NODES * 3072 * 2);   // 25.2 MB
  unsigned short* aggb = (unsigned short*)alloc((size_t)6 * N_NODES * 512 * 2);  // 25.2 MB

  // Areg timeline: xh (16.8, dead after gemm1) -> [wgt12 8.4 | hh 8.4] ->
  // after gemm3: wgt3 (12.6, overlaps dead hh)
  unsigned short* xh = Areg;
  float* wgt12 = (float*)Areg;                           // 4*N*128*4 = 8.39 MB
  unsigned short* hh = Areg + (size_t)N_NODES * 1024;    // second half
  float* wgt3 = (float*)Areg;                            // 6*N*128*4 = 12.6 MB

  float* f1_1 = fbuf;
  float* f2_1 = fbuf + 4 * N_NODES;
  float* f1_2 = fbuf + 8 * N_NODES;
  float* f2_2 = fbuf + 12 * N_NODES;
  float* f1_3 = fbuf + 16 * N_NODES;
  float* f2_3 = fbuf + 22 * N_NODES;

  zero_f<<<(28 * N_NODES + 255) / 256, 256, 0, stream>>>(fbuf, 28 * N_NODES);
  build_csr<<<N_NODES, 256, 0, stream>>>(adj, nbr_cnt, nbr_idx);

  // ---- layer 1: A = x (K=2048), Ntot = 1024, D = 256 ----
  convert_h<<<(N_NODES * 2048 / 4 + 255) / 256, 256, 0, stream>>>(
      x, xh, N_NODES * 2048 / 4);
  convert_w<<<dim3(2048 / 32, 256 / 32, 4), 256, 0, stream>>>(W1, Wt, 2048, 256);
  gemm_mfma<<<dim3(N_NODES / BM, 1024 / BN), 256, 0, stream>>>(
      xh, Wt, Whb, f1_1, f2_1, a1, 2048, 1024, 256);
  attw<<<N_NODES, 256, 0, stream>>>(f1_1, f2_1, nbr_cnt, nbr_idx, wgt12, 4, 1.f);
  gather12<<<8 * (N_NODES / 4), 256, 0, stream>>>(Whb, wgt12, nbr_cnt, nbr_idx, hh);

  // ---- layer 2: A = h (K=1024), Ntot = 1024, D = 256 ----
  convert_w<<<dim3(1024 / 32, 256 / 32, 4), 256, 0, stream>>>(W2, Wt, 1024, 256);
  gemm_mfma<<<dim3(N_NODES / BM, 1024 / BN), 256, 0, stream>>>(
      hh, Wt, Whb, f1_2, f2_2, a2, 1024, 1024, 256);
  attw<<<N_NODES, 256, 0, stream>>>(f1_2, f2_2, nbr_cnt, nbr_idx, wgt12, 4, 1.f);
  gather12<<<8 * (N_NODES / 4), 256, 0, stream>>>(Whb, wgt12, nbr_cnt, nbr_idx, hh);

  // ---- layer 3: A = h (K=1024), Ntot = 3072, D = 512 ----
  convert_w<<<dim3(1024 / 32, 512 / 32, 6), 256, 0, stream>>>(W3, Wt, 1024, 512);
  gemm_mfma<<<dim3(N_NODES / BM, 3072 / BN), 256, 0, stream>>>(
      hh, Wt, Whb, f1_3, f2_3, a3, 1024, 3072, 512);
  attw<<<N_NODES, 256, 0, stream>>>(f1_3, f2_3, nbr_cnt, nbr_idx, wgt3, 6, 1.f / 6.f);
  gather3<<<24 * (N_NODES / 4), 256, 0, stream>>>(Whb, wgt3, nbr_cnt, nbr_idx, aggb);
  reduce3<<<N_NODES, 256, 0, stream>>>(aggb, out);
}